// Round 1
// baseline (102.632 us; speedup 1.0000x reference)
//
#include <hip/hip_runtime.h>
#include <hip/hip_bf16.h>

#define N_TOK 16384
#define B_DIM 8
#define C_DIM 256
#define M_ROWS (N_TOK * B_DIM)   // 131072

typedef __attribute__((ext_vector_type(8))) short short8;
typedef __attribute__((ext_vector_type(4))) float f32x4;

__device__ __forceinline__ unsigned short f2bf(float f) {
    union { float f; unsigned u; } v; v.f = f;
    unsigned r = v.u + 0x7fffu + ((v.u >> 16) & 1u);  // RNE
    return (unsigned short)(r >> 16);
}

// Kernel A: m = (fg_gt != 0) * (1 - mask^T), written to d_out tail.
// Also converts W (C x C fp32) -> bf16 in workspace.
__global__ __launch_bounds__(256)
void prep_kernel(const int* __restrict__ mask, const int* __restrict__ fg,
                 const float* __restrict__ W, unsigned short* __restrict__ Wbf,
                 float* __restrict__ m_out) {
    int i = blockIdx.x * 256 + threadIdx.x;
    if (i < C_DIM * C_DIM) {
        Wbf[i] = f2bf(W[i]);
    }
    if (i < M_ROWS) {
        int b = i & (B_DIM - 1);
        int n = i >> 3;
        float mv = (fg[i] != 0) ? (1.0f - (float)mask[b * N_TOK + n]) : 0.0f;
        m_out[i] = mv;
    }
}

// Kernel B: fused GEMM + relu + masked select.
// Block: 256 threads (4 waves). BM=64 rows, all 256 output cols.
// Wave w covers cols [64w, 64w+64). 4x4 tiles of 16x16x32 bf16 MFMA.
__global__ __launch_bounds__(256)
void mlp_kernel(const float* __restrict__ x, const unsigned short* __restrict__ Wbf,
                const float* __restrict__ bias, const float* __restrict__ m,
                float* __restrict__ out) {
    __shared__ unsigned short lds_x[64 * 256];  // 32 KB, bf16, XOR-swizzled rows

    const int t = threadIdx.x;
    const int row0 = blockIdx.x * 64;

    // ---- Stage x tile (64 x 256 fp32) -> bf16 LDS ----
    // 2048 chunks of 8 elems; 256 threads x 8 iters; coalesced 32B/lane reads.
    #pragma unroll
    for (int j = 0; j < 8; ++j) {
        int ci = j * 256 + t;
        int row = ci >> 5;            // 0..63
        int cc  = (ci & 31) * 8;      // 0..248
        const float4* p = (const float4*)(x + (size_t)(row0 + row) * C_DIM + cc);
        float4 a0 = p[0];
        float4 a1 = p[1];
        unsigned short h[8];
        h[0] = f2bf(a0.x); h[1] = f2bf(a0.y); h[2] = f2bf(a0.z); h[3] = f2bf(a0.w);
        h[4] = f2bf(a1.x); h[5] = f2bf(a1.y); h[6] = f2bf(a1.z); h[7] = f2bf(a1.w);
        int byte = (row * 512 + cc * 2) ^ ((row & 7) << 4);
        *(int4*)((char*)lds_x + byte) = *(const int4*)h;
    }
    __syncthreads();

    // ---- MFMA main loop ----
    const int lane = t & 63;
    const int wid  = t >> 6;
    const int col0 = wid * 64;
    const int lr   = lane & 15;          // row (A) / col (B) within 16-tile
    const int lkb  = (lane >> 4) * 8;    // k-group base (0,8,16,24)

    f32x4 acc[4][4];
    #pragma unroll
    for (int i = 0; i < 4; ++i)
        #pragma unroll
        for (int j = 0; j < 4; ++j)
            acc[i][j] = (f32x4){0.f, 0.f, 0.f, 0.f};

    for (int kk = 0; kk < C_DIM; kk += 32) {
        short8 afrag[4], bfrag[4];
        int c = kk + lkb;
        #pragma unroll
        for (int rt = 0; rt < 4; ++rt) {
            int row = rt * 16 + lr;
            int byte = (row * 512 + c * 2) ^ ((row & 7) << 4);
            afrag[rt] = *(const short8*)((const char*)lds_x + byte);
        }
        #pragma unroll
        for (int ct = 0; ct < 4; ++ct) {
            int d = col0 + ct * 16 + lr;
            bfrag[ct] = *(const short8*)(Wbf + (size_t)d * C_DIM + c);
        }
        #pragma unroll
        for (int rt = 0; rt < 4; ++rt)
            #pragma unroll
            for (int ct = 0; ct < 4; ++ct)
                acc[rt][ct] = __builtin_amdgcn_mfma_f32_16x16x32_bf16(
                    afrag[rt], bfrag[ct], acc[rt][ct], 0, 0, 0);
    }

    // ---- Epilogue: relu(acc + b), select vs fp32 x, write out ----
    float bv[4];
    #pragma unroll
    for (int ct = 0; ct < 4; ++ct)
        bv[ct] = bias[col0 + ct * 16 + lr];

    const int rsub = (lane >> 4) * 4;   // C/D: row = (lane>>4)*4 + reg
    #pragma unroll
    for (int rt = 0; rt < 4; ++rt) {
        #pragma unroll
        for (int r = 0; r < 4; ++r) {
            int row = row0 + rt * 16 + rsub + r;
            float mv = m[row];
            #pragma unroll
            for (int ct = 0; ct < 4; ++ct) {
                int col = col0 + ct * 16 + lr;
                float y = fmaxf(acc[rt][ct][r] + bv[ct], 0.0f);
                float xv = x[(size_t)row * C_DIM + col];
                out[(size_t)row * C_DIM + col] = (mv != 0.0f) ? y : xv;
            }
        }
    }
}

extern "C" void kernel_launch(void* const* d_in, const int* in_sizes, int n_in,
                              void* d_out, int out_size, void* d_ws, size_t ws_size,
                              hipStream_t stream) {
    const float* x    = (const float*)d_in[0];
    const int*   mask = (const int*)d_in[1];
    const int*   fg   = (const int*)d_in[2];
    const float* W    = (const float*)d_in[3];
    const float* b    = (const float*)d_in[4];

    float* out   = (float*)d_out;
    float* m_out = out + (size_t)M_ROWS * C_DIM;          // output 1: m (N,B)
    unsigned short* Wbf = (unsigned short*)d_ws;          // 128 KB scratch

    prep_kernel<<<M_ROWS / 256, 256, 0, stream>>>(mask, fg, W, Wbf, m_out);
    mlp_kernel<<<M_ROWS / 64, 256, 0, stream>>>(x, Wbf, b, m_out, out);
}